// Round 3
// baseline (550.474 us; speedup 1.0000x reference)
//
#include <hip/hip_runtime.h>

// Problem constants (fixed by the reference setup):
//   B=4, FREQ=256, TIME=512, E=512, all float32.
//   out[b, f*TIME+t, e] = x[b, f*TIME+t, e] + pe_1d[f, e] + pe_1d[t, e]
constexpr int B_    = 4;
constexpr int FREQ_ = 256;
constexpr int TIME_ = 512;
constexpr int E_    = 512;
constexpr int E4    = E_ / 4;                     // 128 float4 per row
constexpr long N4   = (long)FREQ_ * TIME_ * E4;   // 2^24 float4 per batch

constexpr int BLOCK = 256;
constexpr int GRID  = 8192;                       // 2^21 threads total
constexpr int ITERS = (int)(N4 / ((long)GRID * BLOCK));  // exactly 8 — compile-time

// native clang vector type — accepted by __builtin_nontemporal_load/store
typedef float f32x4 __attribute__((ext_vector_type(4)));

__global__ void __launch_bounds__(BLOCK)
pe2d_add_kernel(const f32x4* __restrict__ x,
                const f32x4* __restrict__ pe,    // pe_1d as float4, rows of E4
                f32x4* __restrict__ out)
{
    const int i0 = blockIdx.x * BLOCK + threadIdx.x;

    // Compile-time trip count -> compiler can pipeline loads across iterations.
    #pragma unroll 2
    for (int it = 0; it < ITERS; ++it) {
        const int i = i0 + it * (GRID * BLOCK);

        // decompose i -> (f, t, e4); all powers of two -> shifts/masks
        const int e4  = i & (E4 - 1);        // i % 128
        const int row = i >> 7;              // i / 128
        const int t   = row & (TIME_ - 1);   // row % 512
        const int f   = row >> 9;            // row / 512  (< 256)

        // pe is 1 MiB -> keep TEMPORAL (L2-resident, cheap re-reads)
        const f32x4 pf = pe[f * E4 + e4];
        const f32x4 pt = pe[t * E4 + e4];
        const f32x4 ps = pf + pt;

        // reuse the pe sum across all 4 batches; x/out are pure streams ->
        // nontemporal to avoid L2 churn (keeps pe hot, skips write retention)
        #pragma unroll
        for (int b = 0; b < B_; ++b) {
            const size_t idx = (size_t)b * N4 + i;
            f32x4 v = __builtin_nontemporal_load(&x[idx]);
            v += ps;
            __builtin_nontemporal_store(v, &out[idx]);
        }
    }
}

extern "C" void kernel_launch(void* const* d_in, const int* in_sizes, int n_in,
                              void* d_out, int out_size, void* d_ws, size_t ws_size,
                              hipStream_t stream)
{
    const f32x4* x  = (const f32x4*)d_in[0];   // (B, FREQ*TIME, E) fp32
    const f32x4* pe = (const f32x4*)d_in[1];   // (max(F,T)=512, E) fp32
    f32x4* out = (f32x4*)d_out;

    pe2d_add_kernel<<<GRID, BLOCK, 0, stream>>>(x, pe, out);
}

// Round 4
// 412.918 us; speedup vs baseline: 1.3331x; 1.3331x over previous
//
#include <hip/hip_runtime.h>

// out[b, f*TIME+t, e] = x[b, f*TIME+t, e] + pe_1d[f, e] + pe_1d[t, e]
// B=4, FREQ=256, TIME=512, E=512, fp32.
//
// Mapping: each block owns a CONTIGUOUS chunk of BLOCK*ITERS float4.
// Consequences (all alignment-exact, see static_asserts):
//   - e4 = tid & 127 is constant per thread
//   - batch b and freq index f are constant per block  -> pf hoisted
//   - time index t advances by exactly 2 per iteration -> strength-reduced
// Inner loop = 1 L2-hit pe load + 1 HBM load + add + store (copy-like).

typedef float f32x4 __attribute__((ext_vector_type(4)));

constexpr int  B_    = 4;
constexpr int  FREQ_ = 256;
constexpr int  TIME_ = 512;
constexpr int  E_    = 512;
constexpr int  E4    = E_ / 4;                 // 128 float4 per row
constexpr int  ROWS  = FREQ_ * TIME_;          // 131072 rows per batch
constexpr long N4T   = (long)B_ * ROWS * E4;   // 2^26 total float4

constexpr int BLOCK = 256;
constexpr int ITERS = 64;
constexpr int CHUNK = BLOCK * ITERS;           // 16384 float4 = 128 rows per block
constexpr int GRID  = (int)(N4T / CHUNK);      // 4096 blocks

// chunk covers 128 rows, aligned: never crosses an f-group (512 rows) or batch
static_assert(CHUNK % E4 == 0, "chunk row-aligned");
static_assert((CHUNK / E4) <= TIME_ && TIME_ % (CHUNK / E4) == 0, "f const per block");
static_assert(((long)ROWS * E4) % CHUNK == 0, "b const per block");

__global__ void __launch_bounds__(BLOCK)
pe2d_add_kernel(const f32x4* __restrict__ x,
                const f32x4* __restrict__ pe,
                f32x4* __restrict__ out)
{
    const int base    = blockIdx.x * CHUNK;          // < 2^26, fits int
    const int tid     = threadIdx.x;
    const int e4      = tid & (E4 - 1);
    const int dt      = tid >> 7;                    // 0 or 1: second row half
    const int rowbase = (base >> 7) & (ROWS - 1);    // row within batch
    const int f       = rowbase >> 9;                // constant per block
    const f32x4 pf    = pe[f * E4 + e4];             // hoisted freq component

    int i = base + tid;
    int t = (rowbase & (TIME_ - 1)) + dt;            // advances by 2 per iter

    #pragma unroll 4
    for (int it = 0; it < ITERS; ++it) {
        const f32x4 pt = pe[t * E4 + e4];            // L2-hit (pe is 1 MiB)
        f32x4 v = x[i];
        v = v + pf + pt;
        out[i] = v;
        i += BLOCK;                                  // +4 KB per iteration
        t += 2;                                      // 256 float4 = 2 rows
    }
}

extern "C" void kernel_launch(void* const* d_in, const int* in_sizes, int n_in,
                              void* d_out, int out_size, void* d_ws, size_t ws_size,
                              hipStream_t stream)
{
    const f32x4* x  = (const f32x4*)d_in[0];   // (B, FREQ*TIME, E) fp32
    const f32x4* pe = (const f32x4*)d_in[1];   // (512, E) fp32
    f32x4* out = (f32x4*)d_out;

    pe2d_add_kernel<<<GRID, BLOCK, 0, stream>>>(x, pe, out);
}

// Round 5
// 400.776 us; speedup vs baseline: 1.3735x; 1.0303x over previous
//
#include <hip/hip_runtime.h>

// out[b, f*TIME+t, e] = x[b, f*TIME+t, e] + pe_1d[f, e] + pe_1d[t, e]
// B=4, FREQ=256, TIME=512, E=512, fp32.
//
// Mapping (round 3, kept): each block owns a CONTIGUOUS chunk of
// BLOCK*ITERS float4 (128 rows). e4/f/b constant per thread/block,
// t strength-reduced (+2 per iter). Inner loop = 1 L2 pe load +
// 1 HBM load + add + store.
//
// Round 4 change (single lever): nontemporal on the x/out streams.
// x and out are strict one-touch 1 GiB streams; default temporal
// retention lets them evict the 1 MiB pe table from L2 (pe is re-read
// 1024x = 1.07 GB of L2 traffic). nt marks stream lines evict-first,
// protecting pe residency. pe loads stay temporal.

typedef float f32x4 __attribute__((ext_vector_type(4)));

constexpr int  B_    = 4;
constexpr int  FREQ_ = 256;
constexpr int  TIME_ = 512;
constexpr int  E_    = 512;
constexpr int  E4    = E_ / 4;                 // 128 float4 per row
constexpr int  ROWS  = FREQ_ * TIME_;          // 131072 rows per batch
constexpr long N4T   = (long)B_ * ROWS * E4;   // 2^26 total float4

constexpr int BLOCK = 256;
constexpr int ITERS = 64;
constexpr int CHUNK = BLOCK * ITERS;           // 16384 float4 = 128 rows per block
constexpr int GRID  = (int)(N4T / CHUNK);      // 4096 blocks

static_assert(CHUNK % E4 == 0, "chunk row-aligned");
static_assert((CHUNK / E4) <= TIME_ && TIME_ % (CHUNK / E4) == 0, "f const per block");
static_assert(((long)ROWS * E4) % CHUNK == 0, "b const per block");

__global__ void __launch_bounds__(BLOCK)
pe2d_add_kernel(const f32x4* __restrict__ x,
                const f32x4* __restrict__ pe,
                f32x4* __restrict__ out)
{
    const int base    = blockIdx.x * CHUNK;          // < 2^26, fits int
    const int tid     = threadIdx.x;
    const int e4      = tid & (E4 - 1);
    const int dt      = tid >> 7;                    // 0 or 1: second row half
    const int rowbase = (base >> 7) & (ROWS - 1);    // row within batch
    const int f       = rowbase >> 9;                // constant per block
    const f32x4 pf    = pe[f * E4 + e4];             // hoisted freq component

    int i = base + tid;
    int t = (rowbase & (TIME_ - 1)) + dt;            // advances by 2 per iter

    #pragma unroll 4
    for (int it = 0; it < ITERS; ++it) {
        const f32x4 pt = pe[t * E4 + e4];            // temporal: keep in L2
        f32x4 v = __builtin_nontemporal_load(&x[i]); // one-touch stream
        v = v + pf + pt;
        __builtin_nontemporal_store(v, &out[i]);     // one-touch stream
        i += BLOCK;                                  // +4 KB per iteration
        t += 2;                                      // 256 float4 = 2 rows
    }
}

extern "C" void kernel_launch(void* const* d_in, const int* in_sizes, int n_in,
                              void* d_out, int out_size, void* d_ws, size_t ws_size,
                              hipStream_t stream)
{
    const f32x4* x  = (const f32x4*)d_in[0];   // (B, FREQ*TIME, E) fp32
    const f32x4* pe = (const f32x4*)d_in[1];   // (512, E) fp32
    f32x4* out = (f32x4*)d_out;

    pe2d_add_kernel<<<GRID, BLOCK, 0, stream>>>(x, pe, out);
}

// Round 6
// 393.399 us; speedup vs baseline: 1.3993x; 1.0188x over previous
//
#include <hip/hip_runtime.h>

// out[b, f*TIME+t, e] = x[b, f*TIME+t, e] + pe_1d[f, e] + pe_1d[t, e]
// B=4, FREQ=256, TIME=512, E=512, fp32.
//
// Structure (round 3/4, kept): block owns a CONTIGUOUS chunk; e4/f/b constant
// per thread/block; pf hoisted; t strength-reduced; nt on the one-touch x/out
// streams, pe temporal (L2-resident).
//
// Round 5 (tuning only): finer blocks for launch-tail smoothing
// (GRID 4096->16384, ITERS 64->16), deeper pipelining (unroll 8), and
// HBM x-load issued before the L2 pe-load in each body.

typedef float f32x4 __attribute__((ext_vector_type(4)));

constexpr int  B_    = 4;
constexpr int  FREQ_ = 256;
constexpr int  TIME_ = 512;
constexpr int  E_    = 512;
constexpr int  E4    = E_ / 4;                 // 128 float4 per row
constexpr int  ROWS  = FREQ_ * TIME_;          // 131072 rows per batch
constexpr long N4T   = (long)B_ * ROWS * E4;   // 2^26 total float4

constexpr int BLOCK = 256;
constexpr int ITERS = 16;
constexpr int CHUNK = BLOCK * ITERS;           // 4096 float4 = 32 rows per block
constexpr int GRID  = (int)(N4T / CHUNK);      // 16384 blocks

static_assert(CHUNK % E4 == 0, "chunk row-aligned");
static_assert((CHUNK / E4) <= TIME_ && TIME_ % (CHUNK / E4) == 0, "f const per block");
static_assert(((long)ROWS * E4) % CHUNK == 0, "b const per block");

__global__ void __launch_bounds__(BLOCK)
pe2d_add_kernel(const f32x4* __restrict__ x,
                const f32x4* __restrict__ pe,
                f32x4* __restrict__ out)
{
    const int base    = blockIdx.x * CHUNK;          // < 2^26, fits int
    const int tid     = threadIdx.x;
    const int e4      = tid & (E4 - 1);
    const int dt      = tid >> 7;                    // 0 or 1: second row half
    const int rowbase = (base >> 7) & (ROWS - 1);    // row within batch
    const int f       = rowbase >> 9;                // constant per block
    const f32x4 pf    = pe[f * E4 + e4];             // hoisted freq component

    int i = base + tid;
    int t = (rowbase & (TIME_ - 1)) + dt;            // advances by 2 per iter

    #pragma unroll 8
    for (int it = 0; it < ITERS; ++it) {
        f32x4 v = __builtin_nontemporal_load(&x[i]); // HBM load: issue first
        const f32x4 pt = pe[t * E4 + e4];            // L2-hit (pe is 1 MiB)
        v = v + pf + pt;
        __builtin_nontemporal_store(v, &out[i]);     // one-touch stream
        i += BLOCK;                                  // +4 KB per iteration
        t += 2;                                      // 256 float4 = 2 rows
    }
}

extern "C" void kernel_launch(void* const* d_in, const int* in_sizes, int n_in,
                              void* d_out, int out_size, void* d_ws, size_t ws_size,
                              hipStream_t stream)
{
    const f32x4* x  = (const f32x4*)d_in[0];   // (B, FREQ*TIME, E) fp32
    const f32x4* pe = (const f32x4*)d_in[1];   // (512, E) fp32
    f32x4* out = (f32x4*)d_out;

    pe2d_add_kernel<<<GRID, BLOCK, 0, stream>>>(x, pe, out);
}